// Round 1
// baseline (4012.489 us; speedup 1.0000x reference)
//
#include <hip/hip_runtime.h>
#include <stdint.h>

typedef unsigned short u16;
typedef unsigned int   u32;

// Sizes: B=256, T=64, H=256, M2=512, gates=1024
// ws layout (bytes):
//   WattP  bf16 packed [k8<64][h<256][8]  : off 0,       sz 262144
//   WencT  bf16 [m<512][h<256]            : off 262144,  sz 262144
//   WhhP   bf16 packed [j][k8<32][n<1024][8]: off 524288, sz 1048576
//   beff   f32 [256]                      : off 1572864
//   gbias  f32 [2][1024]                  : off 1573888
//   fcE    f32 [515] (514 eff + bias)     : off 1582080

__device__ __forceinline__ float blo(u32 u){ return __uint_as_float(u << 16); }
__device__ __forceinline__ float bhi(u32 u){ return __uint_as_float(u & 0xffff0000u); }
__device__ __forceinline__ float bf2f(u16 v){ return __uint_as_float(((u32)v) << 16); }
__device__ __forceinline__ u16 f2bf(float f){
  u32 u = __float_as_uint(f);
  u += 0x7fffu + ((u >> 16) & 1u);
  return (u16)(u >> 16);
}
__device__ __forceinline__ u32 pk2(float a, float b){
  return (u32)f2bf(a) | (((u32)f2bf(b)) << 16);
}
__device__ __forceinline__ float wave_sum(float v){
  #pragma unroll
  for (int o = 32; o > 0; o >>= 1) v += __shfl_xor(v, o, 64);
  return v;
}
__device__ __forceinline__ float tanh_fast(float x){
  // tanh(x) = 1 - 2/(1+e^{2x}); exp2 handles +-inf saturation correctly
  float e = __builtin_amdgcn_exp2f(x * 2.88539008178f); // 2*log2(e)
  return 1.0f - 2.0f * __builtin_amdgcn_rcpf(1.0f + e);
}
__device__ __forceinline__ float sigm(float x){
  float e = __builtin_amdgcn_exp2f(-x * 1.44269504089f);
  return __builtin_amdgcn_rcpf(1.0f + e);
}

// ---------------- prep kernels ----------------

// Weff = attn_w2 @ attn_w1  (256 x 1024); cols 0..511 -> WattP packed, 512..1023 -> WencT[m][h]
// beff = attn_w2 @ attn_b1 + attn_b2
__global__ __launch_bounds__(256) void prep_attn(
    const float* __restrict__ w1, const float* __restrict__ b1,
    const float* __restrict__ w2, const float* __restrict__ b2,
    u16* __restrict__ WattP, u16* __restrict__ WencT, float* __restrict__ beff)
{
  const int h = blockIdx.x, tid = threadIdx.x;
  __shared__ float w2row[256];
  __shared__ float red[256];
  w2row[tid] = w2[h * 256 + tid];
  __syncthreads();
  float acc0 = 0.f, acc1 = 0.f, acc2 = 0.f, acc3 = 0.f;
  for (int m = 0; m < 256; ++m){
    const float wm = w2row[m];
    const float* r = w1 + m * 1024 + tid;
    acc0 += wm * r[0];
    acc1 += wm * r[256];
    acc2 += wm * r[512];
    acc3 += wm * r[768];
  }
  // k = tid (q=0), tid+256 (q=1) -> attention h/c part
  {
    int k = tid;        WattP[(((k >> 3) * 256 + h) << 3) + (k & 7)] = f2bf(acc0);
  }
  {
    int k = tid + 256;  WattP[(((k >> 3) * 256 + h) << 3) + (k & 7)] = f2bf(acc1);
  }
  // k = tid+512, tid+768 -> enc part, [m][h]
  WencT[(tid      ) * 256 + h] = f2bf(acc2);
  WencT[(tid + 256) * 256 + h] = f2bf(acc3);
  // beff
  red[tid] = w2row[tid] * b1[tid];
  __syncthreads();
  for (int s = 128; s > 0; s >>= 1){
    if (tid < s) red[tid] += red[tid + s];
    __syncthreads();
  }
  if (tid == 0) beff[h] = red[0] + b2[h];
}

// Pack w_hh_{f,b} into [j][k8][n][8] bf16; gbias[j][n] = b_ih + b_hh
__global__ __launch_bounds__(256) void prep_whh(
    const float* __restrict__ whhf, const float* __restrict__ whhb,
    const float* __restrict__ bihf, const float* __restrict__ bhhf,
    const float* __restrict__ bihb, const float* __restrict__ bhhb,
    u16* __restrict__ WhhP, float* __restrict__ gbias)
{
  const int e = blockIdx.x * 256 + threadIdx.x;  // < 524288
  const int j = e >> 18;
  const int r = e & 262143;
  const int n = r >> 8;
  const int k = r & 255;
  const float* w = j ? whhb : whhf;
  WhhP[(size_t)j * 262144 + (((k >> 3) * 1024 + n) << 3) + (k & 7)] = f2bf(w[n * 256 + k]);
  if (e < 2048){
    const int jj = e >> 10, nn = e & 1023;
    gbias[e] = jj ? (bihb[nn] + bhhb[nn]) : (bihf[nn] + bhhf[nn]);
  }
}

// fcE[m] = sum_h fc_w2[h]*fc_w1[h][m] (m<514); fcE[514] = fc_w2 . fc_b1 + fc_b2
__global__ __launch_bounds__(256) void prep_fc(
    const float* __restrict__ fcw1, const float* __restrict__ fcb1,
    const float* __restrict__ fcw2, const float* __restrict__ fcb2,
    float* __restrict__ fcE)
{
  const int tid = threadIdx.x;
  __shared__ float w2s[256];
  __shared__ float red[256];
  w2s[tid] = fcw2[tid];
  __syncthreads();
  for (int m = tid; m < 514; m += 256){
    float a = 0.f;
    for (int hh = 0; hh < 256; ++hh) a += w2s[hh] * fcw1[hh * 514 + m];
    fcE[m] = a;
  }
  red[tid] = w2s[tid] * fcb1[tid];
  __syncthreads();
  for (int s = 128; s > 0; s >>= 1){
    if (tid < s) red[tid] += red[tid + s];
    __syncthreads();
  }
  if (tid == 0) fcE[514] = red[0] + fcb2[0];
}

// ---------------- main kernel: one workgroup per batch element ----------------
__global__ __launch_bounds__(256) void decoder_main(
    const float* __restrict__ enc,   const float* __restrict__ yhist,
    const float* __restrict__ speed, const float* __restrict__ h0,
    const float* __restrict__ c0,    const float* __restrict__ aw3,
    const float* __restrict__ wihf,  const float* __restrict__ wihb,
    const float* __restrict__ fcfw,  const float* __restrict__ fcfb,
    const u16* __restrict__ WattP,   const u16* __restrict__ WencT,
    const u16* __restrict__ WhhP,    const float* __restrict__ beff,
    const float* __restrict__ gbias, const float* __restrict__ fcE,
    float* __restrict__ out)
{
  const int b = blockIdx.x, tid = threadIdx.x;
  const int lane = tid & 63, wv = tid >> 6;

  __shared__ float hcin[2][512];     // [j][k]: k<256 = h, k>=256 = c
  __shared__ float hcp[2][256];      // per-step attention h/c projection
  __shared__ u16   encT[64][256];    // precomputed enc-term, bf16
  __shared__ float ctx[512];
  __shared__ float attw[64];
  __shared__ float attw_acc[64];
  __shared__ float scores[64];
  __shared__ float red[8];
  __shared__ float ytil_s;

  // ---- init state ----
  hcin[0][tid]       = h0[b * 256 + tid];
  hcin[0][256 + tid] = c0[b * 256 + tid];
  hcin[1][tid]       = h0[65536 + b * 256 + tid];
  hcin[1][256 + tid] = c0[65536 + b * 256 + tid];
  if (tid < 64) attw_acc[tid] = 0.f;

  const float* encB = enc + (size_t)b * 32768;

  // ---- prologue: enc_term[s][h] = enc[b,s,:] . WencT[:,h] + beff[h]  (bf16 out)
  {
    const float4 bf4 = *(const float4*)(beff + 4 * lane);
    for (int p = 0; p < 2; ++p){
      float acc[8][4] = {};
      const int sbase = p * 32 + wv * 8;
      for (int m = 0; m < 512; ++m){
        const uint2 wu = *(const uint2*)(WencT + m * 256 + 4 * lane);
        const float q0 = blo(wu.x), q1 = bhi(wu.x), q2 = blo(wu.y), q3 = bhi(wu.y);
        #pragma unroll
        for (int r = 0; r < 8; ++r){
          const float xv = encB[(sbase + r) * 512 + m];   // wave-uniform broadcast
          acc[r][0] += xv * q0; acc[r][1] += xv * q1;
          acc[r][2] += xv * q2; acc[r][3] += xv * q3;
        }
      }
      #pragma unroll
      for (int r = 0; r < 8; ++r){
        const int s = sbase + r;
        uint2 o;
        o.x = pk2(acc[r][0] + bf4.x, acc[r][1] + bf4.y);
        o.y = pk2(acc[r][2] + bf4.z, acc[r][3] + bf4.w);
        *(uint2*)&encT[s][4 * lane] = o;
      }
    }
  }

  // ---- per-thread constants for the step loop ----
  const int nb = tid & 127;
  const int j4 = tid >> 7;
  const float* wih = j4 ? wihb : wihf;
  float wihv[8], gbv[8];
  #pragma unroll
  for (int i = 0; i < 8; ++i){
    wihv[i] = wih[nb + 128 * i];
    gbv[i]  = gbias[j4 * 1024 + nb + 128 * i];
  }
  const float fe0 = fcE[2 * tid], fe1 = fcE[2 * tid + 1];
  const float feY = fcE[512], feS = fcE[513], feB = fcE[514];
  const float w3q0 = aw3[lane], w3q1 = aw3[lane + 64],
              w3q2 = aw3[lane + 128], w3q3 = aw3[lane + 192];
  const int jp = wv & 1;

  // ---- 64 sequential decode steps ----
  for (int t = 0; t < 64; ++t){
    __syncthreads();  // hcin ready (init or previous LSTM update)

    // P1: attention h/c projection: hcp[j][h=tid] = [h_j, c_j] . Weff[:, h]
    {
      float a0 = 0.f, a1 = 0.f;
      #pragma unroll 4
      for (int k8 = 0; k8 < 64; ++k8){
        const uint4 wq = ((const uint4*)WattP)[k8 * 256 + tid];
        const float4 xa = *(const float4*)&hcin[0][k8 * 8];
        const float4 xb = *(const float4*)&hcin[0][k8 * 8 + 4];
        const float4 ya = *(const float4*)&hcin[1][k8 * 8];
        const float4 yb = *(const float4*)&hcin[1][k8 * 8 + 4];
        const float u0 = blo(wq.x), u1 = bhi(wq.x), u2 = blo(wq.y), u3 = bhi(wq.y);
        const float u4 = blo(wq.z), u5 = bhi(wq.z), u6 = blo(wq.w), u7 = bhi(wq.w);
        a0 += u0*xa.x + u1*xa.y + u2*xa.z + u3*xa.w + u4*xb.x + u5*xb.y + u6*xb.z + u7*xb.w;
        a1 += u0*ya.x + u1*ya.y + u2*ya.z + u3*ya.w + u4*yb.x + u5*yb.y + u6*yb.z + u7*yb.w;
      }
      hcp[0][tid] = a0;
      hcp[1][tid] = a1;
    }
    __syncthreads();

    // P2: scores[s] = sum_h w3[h] * tanh(encT[s][h] + hcp[s&1][h]); wave handles s = wv + 4*si
    {
      const float hq0 = hcp[jp][lane],       hq1 = hcp[jp][lane + 64];
      const float hq2 = hcp[jp][lane + 128], hq3 = hcp[jp][lane + 192];
      for (int si = 0; si < 16; ++si){
        const int s = wv + 4 * si;
        float psum = w3q0 * tanh_fast(bf2f(encT[s][lane])       + hq0)
                   + w3q1 * tanh_fast(bf2f(encT[s][lane + 64])  + hq1)
                   + w3q2 * tanh_fast(bf2f(encT[s][lane + 128]) + hq2)
                   + w3q3 * tanh_fast(bf2f(encT[s][lane + 192]) + hq3);
        psum = wave_sum(psum);
        if (lane == 0) scores[s] = psum;
      }
    }
    __syncthreads();

    // softmax over the 64 scores (wave 0)
    if (tid < 64){
      const float v = scores[tid];
      float mx = v;
      #pragma unroll
      for (int o = 32; o > 0; o >>= 1) mx = fmaxf(mx, __shfl_xor(mx, o, 64));
      const float e = __builtin_amdgcn_exp2f((v - mx) * 1.44269504089f);
      float sm = e;
      #pragma unroll
      for (int o = 32; o > 0; o >>= 1) sm += __shfl_xor(sm, o, 64);
      const float a = e / sm;
      attw[tid] = a;
      attw_acc[tid] += a;
    }
    __syncthreads();

    // P3: context[m] = sum_s attw[s]*enc[b,s,m]; then y_tilde
    {
      float ca = 0.f, cb = 0.f;
      const float* ep = encB + 2 * tid;
      #pragma unroll 4
      for (int s = 0; s < 64; ++s){
        const float av = attw[s];
        const float2 ev = *(const float2*)(ep + s * 512);
        ca += av * ev.x; cb += av * ev.y;
      }
      ctx[2 * tid]     = ca;
      ctx[2 * tid + 1] = cb;
      float yp = ca * fe0 + cb * fe1;
      yp = wave_sum(yp);
      if (lane == 0) red[wv] = yp;
    }
    __syncthreads();
    if (tid == 0){
      const float yt = yhist[b * 64 + t];
      const float st = speed[b * 64 + t];
      ytil_s = red[0] + red[1] + red[2] + red[3] + yt * feY + st * feS + feB;
    }
    __syncthreads();

    // P4: LSTM gates + state update. thread: j = tid>>7, owns n = nb+128i, i<8
    {
      float g[8] = {0,0,0,0,0,0,0,0};
      const uint4* whbase = ((const uint4*)WhhP) + (size_t)j4 * 32768;
      #pragma unroll 2
      for (int k8 = 0; k8 < 32; ++k8){
        const float4 xa = *(const float4*)&hcin[j4][k8 * 8];
        const float4 xb = *(const float4*)&hcin[j4][k8 * 8 + 4];
        const uint4* wp = whbase + k8 * 1024 + nb;
        #pragma unroll
        for (int i = 0; i < 8; ++i){
          const uint4 wq = wp[128 * i];
          g[i] += blo(wq.x)*xa.x + bhi(wq.x)*xa.y + blo(wq.y)*xa.z + bhi(wq.y)*xa.w
                + blo(wq.z)*xb.x + bhi(wq.z)*xb.y + blo(wq.w)*xb.z + bhi(wq.w)*xb.w;
        }
      }
      const float yv = ytil_s;
      float hn[2], cn[2];
      #pragma unroll
      for (int r = 0; r < 2; ++r){
        const float pre_i = g[0 + r] + yv * wihv[0 + r] + gbv[0 + r];
        const float pre_f = g[2 + r] + yv * wihv[2 + r] + gbv[2 + r];
        const float pre_g = g[4 + r] + yv * wihv[4 + r] + gbv[4 + r];
        const float pre_o = g[6 + r] + yv * wihv[6 + r] + gbv[6 + r];
        const int p = nb + 128 * r;
        const float cold = hcin[j4][256 + p];
        const float cnew = sigm(pre_f) * cold + sigm(pre_i) * tanh_fast(pre_g);
        cn[r] = cnew;
        hn[r] = sigm(pre_o) * tanh_fast(cnew);
      }
      __syncthreads();  // all gate reads of hcin done before overwrite
      #pragma unroll
      for (int r = 0; r < 2; ++r){
        const int p = nb + 128 * r;
        hcin[j4][p]       = hn[r];
        hcin[j4][256 + p] = cn[r];
      }
    }
  }

  __syncthreads();

  // ---- outputs ----
  if (tid < 64) out[b * 64 + tid] = attw_acc[tid] * 0.015625f;  // /64

  float part = hcin[0][tid] * fcfw[tid]
             + ctx[tid]        * fcfw[256 + tid]
             + ctx[256 + tid]  * fcfw[512 + tid];
  part = wave_sum(part);
  if (lane == 0) red[wv] = part;
  __syncthreads();
  if (tid == 0) out[16384 + b] = red[0] + red[1] + red[2] + red[3] + fcfb[0];
}

// ---------------- launch ----------------
extern "C" void kernel_launch(void* const* d_in, const int* in_sizes, int n_in,
                              void* d_out, int out_size, void* d_ws, size_t ws_size,
                              hipStream_t stream)
{
  const float* enc  = (const float*)d_in[0];
  const float* yh   = (const float*)d_in[1];
  const float* sp   = (const float*)d_in[2];
  const float* h0   = (const float*)d_in[3];
  const float* c0   = (const float*)d_in[4];
  const float* w1   = (const float*)d_in[5];
  const float* b1   = (const float*)d_in[6];
  const float* w2   = (const float*)d_in[7];
  const float* b2   = (const float*)d_in[8];
  const float* w3   = (const float*)d_in[9];
  const float* wihf = (const float*)d_in[11];
  const float* whhf = (const float*)d_in[12];
  const float* bihf = (const float*)d_in[13];
  const float* bhhf = (const float*)d_in[14];
  const float* wihb = (const float*)d_in[15];
  const float* whhb = (const float*)d_in[16];
  const float* bihb = (const float*)d_in[17];
  const float* bhhb = (const float*)d_in[18];
  const float* fcw1 = (const float*)d_in[19];
  const float* fcb1 = (const float*)d_in[20];
  const float* fcw2 = (const float*)d_in[21];
  const float* fcb2 = (const float*)d_in[22];
  const float* fcfw = (const float*)d_in[23];
  const float* fcfb = (const float*)d_in[24];

  char* ws = (char*)d_ws;
  u16*   WattP = (u16*)(ws);
  u16*   WencT = (u16*)(ws + 262144);
  u16*   WhhP  = (u16*)(ws + 524288);
  float* beff  = (float*)(ws + 1572864);
  float* gbias = (float*)(ws + 1573888);
  float* fcE   = (float*)(ws + 1582080);
  float* out   = (float*)d_out;

  prep_attn<<<dim3(256),  dim3(256), 0, stream>>>(w1, b1, w2, b2, WattP, WencT, beff);
  prep_whh <<<dim3(2048), dim3(256), 0, stream>>>(whhf, whhb, bihf, bhhf, bihb, bhhb, WhhP, gbias);
  prep_fc  <<<dim3(1),    dim3(256), 0, stream>>>(fcw1, fcb1, fcw2, fcb2, fcE);
  decoder_main<<<dim3(256), dim3(256), 0, stream>>>(
      enc, yh, sp, h0, c0, w3, wihf, wihb, fcfw, fcfb,
      WattP, WencT, WhhP, beff, gbias, fcE, out);
}

// Round 2
// 1763.220 us; speedup vs baseline: 2.2757x; 2.2757x over previous
//
#include <hip/hip_runtime.h>
#include <stdint.h>

typedef unsigned short u16;
typedef unsigned int   u32;

// Sizes: B=256, T=64, H=256, M2=512, gates=1024
// ws layout (bytes):
//   WattP  bf16 packed [k8<64][h<256][8]  : off 0,       sz 262144
//   WencT  bf16 [m<512][h<256]            : off 262144,  sz 262144
//   WhhP   bf16 packed [j][k8<32][n<1024][8]: off 524288, sz 1048576
//   beff   f32 [256]                      : off 1572864
//   gbias  f32 [2][1024]                  : off 1573888
//   fcE    f32 [515] (514 eff + bias)     : off 1582080

__device__ __forceinline__ float blo(u32 u){ return __uint_as_float(u << 16); }
__device__ __forceinline__ float bhi(u32 u){ return __uint_as_float(u & 0xffff0000u); }
__device__ __forceinline__ float bf2f(u16 v){ return __uint_as_float(((u32)v) << 16); }
__device__ __forceinline__ u16 f2bf(float f){
  u32 u = __float_as_uint(f);
  u += 0x7fffu + ((u >> 16) & 1u);
  return (u16)(u >> 16);
}
__device__ __forceinline__ u32 pk2(float a, float b){
  return (u32)f2bf(a) | (((u32)f2bf(b)) << 16);
}
__device__ __forceinline__ float wave_sum(float v){
  #pragma unroll
  for (int o = 32; o > 0; o >>= 1) v += __shfl_xor(v, o, 64);
  return v;
}
__device__ __forceinline__ float tanh_fast(float x){
  float e = __builtin_amdgcn_exp2f(x * 2.88539008178f); // 2*log2(e)
  return 1.0f - 2.0f * __builtin_amdgcn_rcpf(1.0f + e);
}
__device__ __forceinline__ float sigm(float x){
  float e = __builtin_amdgcn_exp2f(-x * 1.44269504089f);
  return __builtin_amdgcn_rcpf(1.0f + e);
}

// ---------------- prep kernels (unchanged from R1, verified) ----------------

__global__ __launch_bounds__(256) void prep_attn(
    const float* __restrict__ w1, const float* __restrict__ b1,
    const float* __restrict__ w2, const float* __restrict__ b2,
    u16* __restrict__ WattP, u16* __restrict__ WencT, float* __restrict__ beff)
{
  const int h = blockIdx.x, tid = threadIdx.x;
  __shared__ float w2row[256];
  __shared__ float red[256];
  w2row[tid] = w2[h * 256 + tid];
  __syncthreads();
  float acc0 = 0.f, acc1 = 0.f, acc2 = 0.f, acc3 = 0.f;
  for (int m = 0; m < 256; ++m){
    const float wm = w2row[m];
    const float* r = w1 + m * 1024 + tid;
    acc0 += wm * r[0];
    acc1 += wm * r[256];
    acc2 += wm * r[512];
    acc3 += wm * r[768];
  }
  { int k = tid;        WattP[(((k >> 3) * 256 + h) << 3) + (k & 7)] = f2bf(acc0); }
  { int k = tid + 256;  WattP[(((k >> 3) * 256 + h) << 3) + (k & 7)] = f2bf(acc1); }
  WencT[(tid      ) * 256 + h] = f2bf(acc2);
  WencT[(tid + 256) * 256 + h] = f2bf(acc3);
  red[tid] = w2row[tid] * b1[tid];
  __syncthreads();
  for (int s = 128; s > 0; s >>= 1){
    if (tid < s) red[tid] += red[tid + s];
    __syncthreads();
  }
  if (tid == 0) beff[h] = red[0] + b2[h];
}

__global__ __launch_bounds__(256) void prep_whh(
    const float* __restrict__ whhf, const float* __restrict__ whhb,
    const float* __restrict__ bihf, const float* __restrict__ bhhf,
    const float* __restrict__ bihb, const float* __restrict__ bhhb,
    u16* __restrict__ WhhP, float* __restrict__ gbias)
{
  const int e = blockIdx.x * 256 + threadIdx.x;  // < 524288
  const int j = e >> 18;
  const int r = e & 262143;
  const int n = r >> 8;
  const int k = r & 255;
  const float* w = j ? whhb : whhf;
  WhhP[(size_t)j * 262144 + (((k >> 3) * 1024 + n) << 3) + (k & 7)] = f2bf(w[n * 256 + k]);
  if (e < 2048){
    const int jj = e >> 10, nn = e & 1023;
    gbias[e] = jj ? (bihb[nn] + bhhb[nn]) : (bihf[nn] + bhhf[nn]);
  }
}

__global__ __launch_bounds__(256) void prep_fc(
    const float* __restrict__ fcw1, const float* __restrict__ fcb1,
    const float* __restrict__ fcw2, const float* __restrict__ fcb2,
    float* __restrict__ fcE)
{
  const int tid = threadIdx.x;
  __shared__ float w2s[256];
  __shared__ float red[256];
  w2s[tid] = fcw2[tid];
  __syncthreads();
  for (int m = tid; m < 514; m += 256){
    float a = 0.f;
    for (int hh = 0; hh < 256; ++hh) a += w2s[hh] * fcw1[hh * 514 + m];
    fcE[m] = a;
  }
  red[tid] = w2s[tid] * fcb1[tid];
  __syncthreads();
  for (int s = 128; s > 0; s >>= 1){
    if (tid < s) red[tid] += red[tid + s];
    __syncthreads();
  }
  if (tid == 0) fcE[514] = red[0] + fcb2[0];
}

// ---------------- main kernel: 1024 threads (16 waves) per batch element ----------------
__global__ __launch_bounds__(1024) void decoder_main(
    const float* __restrict__ enc,   const float* __restrict__ yhist,
    const float* __restrict__ speed, const float* __restrict__ h0,
    const float* __restrict__ c0,    const float* __restrict__ aw3,
    const float* __restrict__ wihf,  const float* __restrict__ wihb,
    const float* __restrict__ fcfw,  const float* __restrict__ fcfb,
    const u16* __restrict__ WattP,   const u16* __restrict__ WencT,
    const u16* __restrict__ WhhP,    const float* __restrict__ beff,
    const float* __restrict__ gbias, const float* __restrict__ fcE,
    float* __restrict__ out)
{
  const int b = blockIdx.x, tid = threadIdx.x;
  const int lane = tid & 63, wv = tid >> 6;   // wv < 16

  __shared__ float hcin[2][512];     // [j][k]: k<256 = h, k>=256 = c
  __shared__ u16   encT[64][256];    // precomputed enc-term, bf16
  __shared__ float p1part[4][2][256];// P1 k-quarter partials
  __shared__ float ctxp[2][512];     // P3 s-half partials
  __shared__ float ctx[512];
  __shared__ float attw[64];
  __shared__ float attw_acc[64];
  __shared__ float scores[64];
  __shared__ float red[16];
  __shared__ float preS[2][1024];    // LSTM gate pre-activations

  // ---- init state ----
  if (tid < 512){
    const int j = tid >> 8, p = tid & 255;
    hcin[j][p]       = h0[j * 65536 + b * 256 + p];
    hcin[j][256 + p] = c0[j * 65536 + b * 256 + p];
  }
  if (tid < 64) attw_acc[tid] = 0.f;

  const float* encB = enc + (size_t)b * 32768;

  // ---- prologue: enc_term[s][h] = enc[b,s,:] . WencT[:,h] + beff[h] ; wave wv does s=wv*4..wv*4+3
  {
    const float4 bf4 = *(const float4*)(beff + 4 * lane);
    float acc[4][4] = {};
    const int sbase = wv * 4;
    for (int m = 0; m < 512; ++m){
      const uint2 wu = *(const uint2*)(WencT + m * 256 + 4 * lane);
      const float q0 = blo(wu.x), q1 = bhi(wu.x), q2 = blo(wu.y), q3 = bhi(wu.y);
      #pragma unroll
      for (int r = 0; r < 4; ++r){
        const float xv = encB[(sbase + r) * 512 + m];   // wave-uniform broadcast
        acc[r][0] += xv * q0; acc[r][1] += xv * q1;
        acc[r][2] += xv * q2; acc[r][3] += xv * q3;
      }
    }
    #pragma unroll
    for (int r = 0; r < 4; ++r){
      const int s = sbase + r;
      uint2 o;
      o.x = pk2(acc[r][0] + bf4.x, acc[r][1] + bf4.y);
      o.y = pk2(acc[r][2] + bf4.z, acc[r][3] + bf4.w);
      *(uint2*)&encT[s][4 * lane] = o;
    }
  }

  // ---- per-thread constants ----
  const int h1 = tid & 255, kq = tid >> 8;          // P1: h, k-quarter
  const int m3 = tid & 511, sh = tid >> 9;          // P3: m, s-half
  const int nn = tid & 511, j4 = tid >> 9;          // P4: gate cols nn, nn+512; lstm j
  const float* wih = j4 ? wihb : wihf;
  const float wih0 = wih[nn], wih1 = wih[nn + 512];
  const float gb0  = gbias[j4 * 1024 + nn], gb1 = gbias[j4 * 1024 + nn + 512];
  const float fe   = fcE[m3];
  const float feY = fcE[512], feS = fcE[513], feB = fcE[514];
  const float w3q0 = aw3[lane], w3q1 = aw3[lane + 64],
              w3q2 = aw3[lane + 128], w3q3 = aw3[lane + 192];

  // ---- 64 sequential decode steps ----
  for (int t = 0; t < 64; ++t){
    __syncthreads();  // S0: hcin (and encT on t=0) ready

    // P1: attention h/c projection partials; thread = (h1, kq), 16 k8 each
    {
      float a0 = 0.f, a1 = 0.f;
      const uint4* wp = ((const uint4*)WattP) + (kq * 16) * 256 + h1;
      const int kb = kq * 16;
      #pragma unroll 4
      for (int i = 0; i < 16; ++i){
        const uint4 wq = wp[i * 256];
        const float4 xa = *(const float4*)&hcin[0][(kb + i) * 8];
        const float4 xb = *(const float4*)&hcin[0][(kb + i) * 8 + 4];
        const float4 ya = *(const float4*)&hcin[1][(kb + i) * 8];
        const float4 yb = *(const float4*)&hcin[1][(kb + i) * 8 + 4];
        const float u0 = blo(wq.x), u1 = bhi(wq.x), u2 = blo(wq.y), u3 = bhi(wq.y);
        const float u4 = blo(wq.z), u5 = bhi(wq.z), u6 = blo(wq.w), u7 = bhi(wq.w);
        a0 += u0*xa.x + u1*xa.y + u2*xa.z + u3*xa.w + u4*xb.x + u5*xb.y + u6*xb.z + u7*xb.w;
        a1 += u0*ya.x + u1*ya.y + u2*ya.z + u3*ya.w + u4*yb.x + u5*yb.y + u6*yb.z + u7*yb.w;
      }
      p1part[kq][0][h1] = a0;
      p1part[kq][1][h1] = a1;
    }
    __syncthreads();  // S1: p1part ready

    // P2: scores; wave wv handles s = wv*4 + r. hcp reduction folded in.
    {
      float hqA[4], hqB[4];
      #pragma unroll
      for (int q = 0; q < 4; ++q){
        const int hh = lane + 64 * q;
        hqA[q] = p1part[0][0][hh] + p1part[1][0][hh] + p1part[2][0][hh] + p1part[3][0][hh];
        hqB[q] = p1part[0][1][hh] + p1part[1][1][hh] + p1part[2][1][hh] + p1part[3][1][hh];
      }
      #pragma unroll
      for (int r = 0; r < 4; ++r){
        const int s = wv * 4 + r;
        const float* hq = (s & 1) ? hqB : hqA;
        float psum = w3q0 * tanh_fast(bf2f(encT[s][lane])       + hq[0])
                   + w3q1 * tanh_fast(bf2f(encT[s][lane + 64])  + hq[1])
                   + w3q2 * tanh_fast(bf2f(encT[s][lane + 128]) + hq[2])
                   + w3q3 * tanh_fast(bf2f(encT[s][lane + 192]) + hq[3]);
        psum = wave_sum(psum);
        if (lane == 0) scores[s] = psum;
      }
    }
    __syncthreads();  // S2: scores ready

    // softmax over 64 scores (wave 0)
    if (tid < 64){
      const float v = scores[tid];
      float mx = v;
      #pragma unroll
      for (int o = 32; o > 0; o >>= 1) mx = fmaxf(mx, __shfl_xor(mx, o, 64));
      const float e = __builtin_amdgcn_exp2f((v - mx) * 1.44269504089f);
      float sm = e;
      #pragma unroll
      for (int o = 32; o > 0; o >>= 1) sm += __shfl_xor(sm, o, 64);
      const float a = e / sm;
      attw[tid] = a;
      attw_acc[tid] += a;
    }
    __syncthreads();  // S3: attw ready

    // P3: context partials; thread = (m3, sh), 32 s each
    {
      float ca = 0.f;
      const float* ep = encB + m3 + sh * 16384;   // s = sh*32 .. +32
      #pragma unroll 4
      for (int s = 0; s < 32; ++s)
        ca += attw[sh * 32 + s] * ep[s * 512];
      ctxp[sh][m3] = ca;
    }
    __syncthreads();  // S4: ctxp ready

    if (tid < 512){
      const float c = ctxp[0][tid] + ctxp[1][tid];
      ctx[tid] = c;
      float yp = c * fe;
      yp = wave_sum(yp);
      if (lane == 0) red[wv] = yp;
    }
    __syncthreads();  // S5: red ready

    const float yt = yhist[b * 64 + t];
    const float st = speed[b * 64 + t];
    const float ytil = (red[0] + red[1] + red[2] + red[3] +
                        red[4] + red[5] + red[6] + red[7]) +
                       yt * feY + st * feS + feB;

    // P4: LSTM gate dots; thread = (j4, nn) owns gates nn and nn+512
    {
      float g0 = 0.f, g1 = 0.f;
      const uint4* wp = ((const uint4*)WhhP) + (size_t)j4 * 32768 + nn;
      #pragma unroll 4
      for (int k8 = 0; k8 < 32; ++k8){
        const float4 xa = *(const float4*)&hcin[j4][k8 * 8];
        const float4 xb = *(const float4*)&hcin[j4][k8 * 8 + 4];
        const uint4 w0 = wp[k8 * 1024];
        const uint4 w1 = wp[k8 * 1024 + 512];
        g0 += blo(w0.x)*xa.x + bhi(w0.x)*xa.y + blo(w0.y)*xa.z + bhi(w0.y)*xa.w
            + blo(w0.z)*xb.x + bhi(w0.z)*xb.y + blo(w0.w)*xb.z + bhi(w0.w)*xb.w;
        g1 += blo(w1.x)*xa.x + bhi(w1.x)*xa.y + blo(w1.y)*xa.z + bhi(w1.y)*xa.w
            + blo(w1.z)*xb.x + bhi(w1.z)*xb.y + blo(w1.w)*xb.z + bhi(w1.w)*xb.w;
      }
      preS[j4][nn]       = g0 + ytil * wih0 + gb0;
      preS[j4][nn + 512] = g1 + ytil * wih1 + gb1;
    }
    __syncthreads();  // S6: preS ready (and all hcin h-reads done)

    if (tid < 512){
      const int j = tid >> 8, p = tid & 255;
      const float pi = preS[j][p],       pf = preS[j][p + 256];
      const float pg = preS[j][p + 512], po = preS[j][p + 768];
      const float cold = hcin[j][256 + p];
      const float cnew = sigm(pf) * cold + sigm(pi) * tanh_fast(pg);
      hcin[j][256 + p] = cnew;
      hcin[j][p]       = sigm(po) * tanh_fast(cnew);
    }
  }

  __syncthreads();

  // ---- outputs ----
  if (tid < 64) out[b * 64 + tid] = attw_acc[tid] * 0.015625f;  // /64

  if (tid < 256){
    float part = hcin[0][tid]     * fcfw[tid]
               + ctx[tid]         * fcfw[256 + tid]
               + ctx[256 + tid]   * fcfw[512 + tid];
    part = wave_sum(part);
    if (lane == 0) red[wv] = part;
  }
  __syncthreads();
  if (tid == 0) out[16384 + b] = red[0] + red[1] + red[2] + red[3] + fcfb[0];
}

// ---------------- launch ----------------
extern "C" void kernel_launch(void* const* d_in, const int* in_sizes, int n_in,
                              void* d_out, int out_size, void* d_ws, size_t ws_size,
                              hipStream_t stream)
{
  const float* enc  = (const float*)d_in[0];
  const float* yh   = (const float*)d_in[1];
  const float* sp   = (const float*)d_in[2];
  const float* h0   = (const float*)d_in[3];
  const float* c0   = (const float*)d_in[4];
  const float* w1   = (const float*)d_in[5];
  const float* b1   = (const float*)d_in[6];
  const float* w2   = (const float*)d_in[7];
  const float* b2   = (const float*)d_in[8];
  const float* w3   = (const float*)d_in[9];
  const float* wihf = (const float*)d_in[11];
  const float* whhf = (const float*)d_in[12];
  const float* bihf = (const float*)d_in[13];
  const float* bhhf = (const float*)d_in[14];
  const float* wihb = (const float*)d_in[15];
  const float* whhb = (const float*)d_in[16];
  const float* bihb = (const float*)d_in[17];
  const float* bhhb = (const float*)d_in[18];
  const float* fcw1 = (const float*)d_in[19];
  const float* fcb1 = (const float*)d_in[20];
  const float* fcw2 = (const float*)d_in[21];
  const float* fcb2 = (const float*)d_in[22];
  const float* fcfw = (const float*)d_in[23];
  const float* fcfb = (const float*)d_in[24];

  char* ws = (char*)d_ws;
  u16*   WattP = (u16*)(ws);
  u16*   WencT = (u16*)(ws + 262144);
  u16*   WhhP  = (u16*)(ws + 524288);
  float* beff  = (float*)(ws + 1572864);
  float* gbias = (float*)(ws + 1573888);
  float* fcE   = (float*)(ws + 1582080);
  float* out   = (float*)d_out;

  prep_attn<<<dim3(256),  dim3(256), 0, stream>>>(w1, b1, w2, b2, WattP, WencT, beff);
  prep_whh <<<dim3(2048), dim3(256), 0, stream>>>(whhf, whhb, bihf, bhhf, bihb, bhhb, WhhP, gbias);
  prep_fc  <<<dim3(1),    dim3(256), 0, stream>>>(fcw1, fcb1, fcw2, fcb2, fcE);
  decoder_main<<<dim3(256), dim3(1024), 0, stream>>>(
      enc, yh, sp, h0, c0, w3, wihf, wihb, fcfw, fcfb,
      WattP, WencT, WhhP, beff, gbias, fcE, out);
}